// Round 1
// baseline (5413.675 us; speedup 1.0000x reference)
//
#include <hip/hip_runtime.h>
#include <math.h>

// Problem constants
constexpr int EMBED  = 1024;
constexpr int NHEADS = 16;
constexpr int HDIM   = 64;
constexpr int BATCH  = 2;
constexpr int SEQ    = 2048;
constexpr int MROWS  = BATCH * SEQ;  // 4096

#define TS 16

// C[i,j] = sum_m A[m,i] * A[m,j]   (A^T A), A is [M,N] row-major, C is [N,N]
__global__ void gemm_ata(const float* __restrict__ A, float* __restrict__ C,
                         int M, int N) {
    __shared__ float As[TS][TS + 1];
    __shared__ float Bs[TS][TS + 1];
    const int tx = threadIdx.x, ty = threadIdx.y;
    const int i0 = blockIdx.y * TS, j0 = blockIdx.x * TS;
    float acc = 0.f;
    for (int m0 = 0; m0 < M; m0 += TS) {
        As[ty][tx] = A[(size_t)(m0 + ty) * N + i0 + tx];
        Bs[ty][tx] = A[(size_t)(m0 + ty) * N + j0 + tx];
        __syncthreads();
#pragma unroll
        for (int mm = 0; mm < TS; ++mm)
            acc += As[mm][ty] * Bs[mm][tx];
        __syncthreads();
    }
    C[(size_t)(i0 + ty) * N + j0 + tx] = acc;
}

// C[i,j] = W[i,j] - sum_l W[i,l] * G[l,j]   (orthogonalized weight), all [N,N]
__global__ void gemm_orth(const float* __restrict__ W, const float* __restrict__ G,
                          float* __restrict__ C, int N) {
    __shared__ float Ws[TS][TS + 1];
    __shared__ float Gs[TS][TS + 1];
    const int tx = threadIdx.x, ty = threadIdx.y;
    const int i0 = blockIdx.y * TS, j0 = blockIdx.x * TS;
    float acc = 0.f;
    for (int l0 = 0; l0 < N; l0 += TS) {
        Ws[ty][tx] = W[(size_t)(i0 + ty) * N + l0 + tx];
        Gs[ty][tx] = G[(size_t)(l0 + ty) * N + j0 + tx];
        __syncthreads();
#pragma unroll
        for (int ll = 0; ll < TS; ++ll)
            acc += Ws[ty][ll] * Gs[ll][tx];
        __syncthreads();
    }
    const size_t idx = (size_t)(i0 + ty) * N + j0 + tx;
    C[idx] = W[idx] - acc;
}

// C[m,n] = sum_k A[m,k] * B[n,k]   (x @ W^T);  A [M,K], B [N,K], C [M,N]
__global__ void gemm_nt(const float* __restrict__ A, const float* __restrict__ B,
                        float* __restrict__ C, int M, int N, int K) {
    __shared__ float As[TS][TS + 1];
    __shared__ float Bs[TS][TS + 1];
    const int tx = threadIdx.x, ty = threadIdx.y;
    const int m0 = blockIdx.y * TS, n0 = blockIdx.x * TS;
    float acc = 0.f;
    for (int k0 = 0; k0 < K; k0 += TS) {
        As[ty][tx] = A[(size_t)(m0 + ty) * K + k0 + tx];
        Bs[ty][tx] = B[(size_t)(n0 + ty) * K + k0 + tx];
        __syncthreads();
#pragma unroll
        for (int kk = 0; kk < TS; ++kk)
            acc += As[ty][kk] * Bs[tx][kk];
        __syncthreads();
    }
    C[(size_t)(m0 + ty) * N + n0 + tx] = acc;
}

// Flash attention, fp32, online softmax. Layout: Q/K/V/O are [B, S, E] with
// head h occupying columns [h*64, h*64+64). One block = one (b, h, 16-row
// query tile); loops over all 128 key tiles of 16.
__global__ void flash_attn(const float* __restrict__ Q, const float* __restrict__ K,
                           const float* __restrict__ V, float* __restrict__ O) {
    const int qt = blockIdx.x, h = blockIdx.y, b = blockIdx.z;
    const int t = threadIdx.x;  // 256 threads

    __shared__ float qs[16][HDIM + 1];
    __shared__ float ks[16][HDIM + 1];
    __shared__ float vs[16][HDIM + 1];
    __shared__ float sc[16][TS + 1];
    __shared__ float oacc[16][HDIM + 1];
    __shared__ float mrow[16], lrow[16], arow[16];

    const float scale = 0.125f;  // 1/sqrt(64)
    const size_t base = (size_t)b * SEQ * EMBED + (size_t)h * HDIM;

#pragma unroll
    for (int r = 0; r < 4; ++r) {
        int idx = t + 256 * r;
        int i = idx >> 6, d = idx & 63;
        qs[i][d] = Q[base + (size_t)(qt * 16 + i) * EMBED + d] * scale;
        oacc[i][d] = 0.f;
    }
    if (t < 16) { mrow[t] = -INFINITY; lrow[t] = 0.f; }
    __syncthreads();

    for (int kt = 0; kt < SEQ / 16; ++kt) {
#pragma unroll
        for (int r = 0; r < 4; ++r) {
            int idx = t + 256 * r;
            int i = idx >> 6, d = idx & 63;
            ks[i][d] = K[base + (size_t)(kt * 16 + i) * EMBED + d];
            vs[i][d] = V[base + (size_t)(kt * 16 + i) * EMBED + d];
        }
        __syncthreads();

        // scores: 256 threads -> 16x16 tile
        {
            const int i = t >> 4, j = t & 15;
            float s = 0.f;
#pragma unroll
            for (int d = 0; d < HDIM; ++d) s += qs[i][d] * ks[j][d];
            sc[i][j] = s;
        }
        __syncthreads();

        // online-softmax state update (one thread per row)
        if (t < 16) {
            const float m_old = mrow[t];
            float mx = m_old;
#pragma unroll
            for (int j = 0; j < 16; ++j) mx = fmaxf(mx, sc[t][j]);
            const float al = expf(m_old - mx);  // 0 when m_old = -inf
            float ls = 0.f;
#pragma unroll
            for (int j = 0; j < 16; ++j) {
                const float p = expf(sc[t][j] - mx);
                sc[t][j] = p;
                ls += p;
            }
            mrow[t] = mx;
            lrow[t] = lrow[t] * al + ls;
            arow[t] = al;
        }
        __syncthreads();

        // O accumulator update
#pragma unroll
        for (int r = 0; r < 4; ++r) {
            int idx = t + 256 * r;
            int i = idx >> 6, d = idx & 63;
            float o = oacc[i][d] * arow[i];
#pragma unroll
            for (int j = 0; j < 16; ++j) o += sc[i][j] * vs[j][d];
            oacc[i][d] = o;
        }
        __syncthreads();  // before next tile overwrites ks/vs/sc
    }

#pragma unroll
    for (int r = 0; r < 4; ++r) {
        int idx = t + 256 * r;
        int i = idx >> 6, d = idx & 63;
        O[base + (size_t)(qt * 16 + i) * EMBED + d] = oacc[i][d] / lrow[i];
    }
}

extern "C" void kernel_launch(void* const* d_in, const int* in_sizes, int n_in,
                              void* d_out, int out_size, void* d_ws, size_t ws_size,
                              hipStream_t stream) {
    const float* query = (const float*)d_in[0];
    const float* key_  = (const float*)d_in[1];
    const float* value = (const float*)d_in[2];
    const float* Wq    = (const float*)d_in[3];
    const float* Wk    = (const float*)d_in[4];
    const float* Wv    = (const float*)d_in[5];
    const float* Wo    = (const float*)d_in[6];
    float* out = (float*)d_out;

    // Workspace layout (floats): needs 20M floats = 80 MB
    float* ws  = (float*)d_ws;
    const size_t MEGA = 1024 * 1024;
    float* Gq  = ws + 0 * MEGA;   // [1024,1024]
    float* Gk  = ws + 1 * MEGA;
    float* Wqo = ws + 2 * MEGA;
    float* Wko = ws + 3 * MEGA;
    float* q   = ws + 4 * MEGA;   // [4096,1024]
    float* k   = ws + 8 * MEGA;
    float* v   = ws + 12 * MEGA;
    float* ao  = ws + 16 * MEGA;  // attention output, [4096,1024]

    dim3 blk(TS, TS);
    dim3 g64(EMBED / TS, EMBED / TS);

    // 1) Gram matrices from ORIGINAL weights
    gemm_ata<<<g64, blk, 0, stream>>>(Wq, Gq, EMBED, EMBED);
    gemm_ata<<<g64, blk, 0, stream>>>(Wk, Gk, EMBED, EMBED);
    // 2) Orthogonalized weights (both from originals)
    gemm_orth<<<g64, blk, 0, stream>>>(Wq, Gk, Wqo, EMBED);
    gemm_orth<<<g64, blk, 0, stream>>>(Wk, Gq, Wko, EMBED);
    // 3) Projections  x @ W^T
    dim3 gproj(EMBED / TS, MROWS / TS);
    gemm_nt<<<gproj, blk, 0, stream>>>(query, Wqo, q, MROWS, EMBED, EMBED);
    gemm_nt<<<gproj, blk, 0, stream>>>(key_,  Wko, k, MROWS, EMBED, EMBED);
    gemm_nt<<<gproj, blk, 0, stream>>>(value, Wv,  v, MROWS, EMBED, EMBED);
    // 4) Attention (flash-style, heads stay interleaved in E dim)
    dim3 gattn(SEQ / 16, NHEADS, BATCH);
    flash_attn<<<gattn, dim3(256), 0, stream>>>(q, k, v, ao);
    // 5) Output projection
    gemm_nt<<<gproj, blk, 0, stream>>>(ao, Wo, out, MROWS, EMBED, EMBED);
}

// Round 2
// 608.986 us; speedup vs baseline: 8.8896x; 8.8896x over previous
//
#include <hip/hip_runtime.h>
#include <math.h>

constexpr int EMBED  = 1024;
constexpr int NHEADS = 16;
constexpr int HDIM   = 64;
constexpr int BATCH  = 2;
constexpr int SEQ    = 2048;
constexpr int MROWS  = BATCH * SEQ;  // 4096

typedef unsigned short u16b;  // bf16 storage
typedef __attribute__((ext_vector_type(8))) short bfrag;   // 8 bf16 (4 VGPRs)
typedef __attribute__((ext_vector_type(4))) float ffrag;   // 4 fp32 acc

__device__ __forceinline__ u16b f2b(float f) {
    union { float f; unsigned u; } v; v.f = f;
    unsigned r = v.u + 0x7fffu + ((v.u >> 16) & 1u);  // RNE
    return (u16b)(r >> 16);
}

__device__ __forceinline__ void gload_lds16(const u16b* g, u16b* l) {
    // async 16B/lane global->LDS; LDS dest = wave-uniform base + lane*16
    __builtin_amdgcn_global_load_lds(
        (const __attribute__((address_space(1))) void*)g,
        (__attribute__((address_space(3))) void*)l,
        16, 0, 0);
}

// ---------- conversion / transpose helpers ----------

// fp32 -> bf16, n multiple of 4
__global__ void convert_f2b(const float* __restrict__ in, u16b* __restrict__ out, int n) {
    int i = blockIdx.x * 256 + threadIdx.x;
    if (i * 4 >= n) return;
    float4 v = ((const float4*)in)[i];
    ushort4 o;
    o.x = f2b(v.x); o.y = f2b(v.y); o.z = f2b(v.z); o.w = f2b(v.w);
    ((ushort4*)out)[i] = o;
}

// fp32 [n,n] -> bf16 transposed [n,n]
__global__ void transpose_f2b(const float* __restrict__ in, u16b* __restrict__ out, int n) {
    __shared__ float t[32][33];
    const int bx = blockIdx.x * 32, by = blockIdx.y * 32;
    const int x = threadIdx.x, y = threadIdx.y;  // (32,8)
#pragma unroll
    for (int r = 0; r < 4; ++r)
        t[y + 8 * r][x] = in[(size_t)(by + y + 8 * r) * n + bx + x];
    __syncthreads();
#pragma unroll
    for (int r = 0; r < 4; ++r)
        out[(size_t)(bx + y + 8 * r) * n + by + x] = f2b(t[x][y + 8 * r]);
}

// bf16 v [B,S,E] -> Vt [B,H,64,S]
__global__ void transpose_v(const u16b* __restrict__ vp, u16b* __restrict__ Vt) {
    __shared__ u16b t[64][65];
    const int s0 = blockIdx.x * 64, h = blockIdx.y, b = blockIdx.z;
    const int x = threadIdx.x, y = threadIdx.y;  // (64,4)
#pragma unroll
    for (int r = 0; r < 16; ++r) {
        int srow = y + 4 * r;
        t[srow][x] = vp[(size_t)(b * SEQ + s0 + srow) * EMBED + h * HDIM + x];
    }
    __syncthreads();
#pragma unroll
    for (int r = 0; r < 16; ++r) {
        int d = y + 4 * r;
        Vt[(size_t)((b * NHEADS + h) * HDIM + d) * SEQ + s0 + x] = t[x][d];
    }
}

// ---------- bf16 MFMA NT GEMM ----------
// C[M,N] = A[M,K] @ B[N,K]^T  (both row-major bf16, k contiguous)
// MODE 0: Cb = f2b(AB)   MODE 1: Cb = f2b(D - AB), D fp32   MODE 2: Cf = AB (fp32)
template<int MODE>
__global__ __launch_bounds__(256) void gemm_nt_mfma(
    const u16b* __restrict__ A, const u16b* __restrict__ B,
    const float* __restrict__ D, u16b* __restrict__ Cb, float* __restrict__ Cf,
    int M, int N, int K)
{
    constexpr int BM = 128, BN = 128, BK = 32;
    __shared__ __align__(16) u16b As[BM * BK];
    __shared__ __align__(16) u16b Bs[BN * BK];

    const int tid  = threadIdx.x;
    const int wave = tid >> 6, lane = tid & 63;
    const int quad = lane >> 4, l16 = lane & 15;
    const int wrow = wave >> 1, wcol = wave & 1;          // 2x2 wave grid
    const int m0 = blockIdx.y * BM, n0 = blockIdx.x * BN;

    ffrag acc[4][4];
#pragma unroll
    for (int i = 0; i < 4; ++i)
#pragma unroll
        for (int j = 0; j < 4; ++j) acc[i][j] = ffrag{0.f, 0.f, 0.f, 0.f};

    const int srow = lane >> 2, schunk = lane & 3;        // staging: 16 rows x 4 chunks / issue

    for (int kt = 0; kt < K; kt += BK) {
        // stage A,B tiles: per wave 2 issues each (16 rows x 64B)
#pragma unroll
        for (int q = 0; q < 2; ++q) {
            int row = wave * 32 + q * 16;
            gload_lds16(A + (size_t)(m0 + row + srow) * K + kt + schunk * 8, &As[row * BK]);
            gload_lds16(B + (size_t)(n0 + row + srow) * K + kt + schunk * 8, &Bs[row * BK]);
        }
        __syncthreads();

        bfrag af[4], bfv[4];
#pragma unroll
        for (int i = 0; i < 4; ++i)
            af[i] = *(const bfrag*)&As[(wrow * 64 + i * 16 + l16) * BK + quad * 8];
#pragma unroll
        for (int j = 0; j < 4; ++j)
            bfv[j] = *(const bfrag*)&Bs[(wcol * 64 + j * 16 + l16) * BK + quad * 8];
#pragma unroll
        for (int i = 0; i < 4; ++i)
#pragma unroll
            for (int j = 0; j < 4; ++j)
                acc[i][j] = __builtin_amdgcn_mfma_f32_16x16x32_bf16(af[i], bfv[j], acc[i][j], 0, 0, 0);
        __syncthreads();
    }

#pragma unroll
    for (int i = 0; i < 4; ++i)
#pragma unroll
        for (int j = 0; j < 4; ++j) {
            const int col = n0 + wcol * 64 + j * 16 + l16;
#pragma unroll
            for (int r = 0; r < 4; ++r) {
                const int row = m0 + wrow * 64 + i * 16 + quad * 4 + r;
                const size_t idx = (size_t)row * N + col;
                const float v = acc[i][j][r];
                if (MODE == 0) Cb[idx] = f2b(v);
                else if (MODE == 1) Cb[idx] = f2b(D[idx] - v);
                else Cf[idx] = v;
            }
        }
}

// ---------- flash attention, bf16 MFMA ----------
// Q,K: [B,S,E] bf16 (head h = cols h*64..); Vt: [B,H,64,S] bf16; O: [B,S,E] bf16
__global__ __launch_bounds__(256) void flash_attn_mfma(
    const u16b* __restrict__ Q, const u16b* __restrict__ Km,
    const u16b* __restrict__ Vt, u16b* __restrict__ Oo)
{
    const int tid = threadIdx.x;
    const int wave = tid >> 6, lane = tid & 63;
    const int quad = lane >> 4, l16 = lane & 15;
    const int qt = blockIdx.x, h = blockIdx.y, b = blockIdx.z;
    const int q0 = qt * 64 + wave * 16;  // this wave's 16 q-rows

    __shared__ __align__(16) u16b Ps[4][16][72];  // per-wave P tile, +8 pad

    const size_t qkbase = (size_t)b * SEQ * EMBED + h * HDIM;
    const size_t vtbase = (size_t)(b * NHEADS + h) * HDIM * SEQ;

    // Q fragments (A-layout): rows l16, dims s*32 + quad*8 + j
    bfrag aq[2];
#pragma unroll
    for (int s = 0; s < 2; ++s)
        aq[s] = *(const bfrag*)&Q[qkbase + (size_t)(q0 + l16) * EMBED + s * 32 + quad * 8];

    ffrag ov[4];
    float mr[4], lr[4];
#pragma unroll
    for (int t = 0; t < 4; ++t) ov[t] = ffrag{0.f, 0.f, 0.f, 0.f};
#pragma unroll
    for (int r = 0; r < 4; ++r) { mr[r] = -1e30f; lr[r] = 0.f; }

    for (int kt = 0; kt < SEQ; kt += 64) {
        // --- S = Q K^T (16 q-rows x 64 keys) ---
        ffrag sc[4];
#pragma unroll
        for (int t = 0; t < 4; ++t) sc[t] = ffrag{0.f, 0.f, 0.f, 0.f};
#pragma unroll
        for (int t = 0; t < 4; ++t) {
            const u16b* krow = &Km[qkbase + (size_t)(kt + t * 16 + l16) * EMBED];
#pragma unroll
            for (int s = 0; s < 2; ++s) {
                bfrag bk = *(const bfrag*)(krow + s * 32 + quad * 8);
                sc[t] = __builtin_amdgcn_mfma_f32_16x16x32_bf16(aq[s], bk, sc[t], 0, 0, 0);
            }
        }
        // scale
#pragma unroll
        for (int t = 0; t < 4; ++t)
#pragma unroll
            for (int r = 0; r < 4; ++r) sc[t][r] *= 0.125f;

        // --- online softmax (per C-row = quad*4+r; reduce across 16-lane quad) ---
        float al[4];
#pragma unroll
        for (int r = 0; r < 4; ++r) {
            float mx = -1e30f;
#pragma unroll
            for (int t = 0; t < 4; ++t) mx = fmaxf(mx, sc[t][r]);
            mx = fmaxf(mx, __shfl_xor(mx, 1));
            mx = fmaxf(mx, __shfl_xor(mx, 2));
            mx = fmaxf(mx, __shfl_xor(mx, 4));
            mx = fmaxf(mx, __shfl_xor(mx, 8));
            const float mnew = fmaxf(mr[r], mx);
            al[r] = __expf(mr[r] - mnew);
            mr[r] = mnew;
            float rs = 0.f;
#pragma unroll
            for (int t = 0; t < 4; ++t) {
                float p = __expf(sc[t][r] - mnew);
                sc[t][r] = p;
                rs += p;
            }
            rs += __shfl_xor(rs, 1);
            rs += __shfl_xor(rs, 2);
            rs += __shfl_xor(rs, 4);
            rs += __shfl_xor(rs, 8);
            lr[r] = lr[r] * al[r] + rs;
        }
#pragma unroll
        for (int t = 0; t < 4; ++t)
#pragma unroll
            for (int r = 0; r < 4; ++r) ov[t][r] *= al[r];

        // --- P: C-layout -> A-layout via per-wave LDS round-trip ---
#pragma unroll
        for (int t = 0; t < 4; ++t)
#pragma unroll
            for (int r = 0; r < 4; ++r)
                Ps[wave][quad * 4 + r][t * 16 + l16] = f2b(sc[t][r]);
        asm volatile("s_waitcnt lgkmcnt(0)" ::: "memory");
        bfrag ap[2];
#pragma unroll
        for (int s = 0; s < 2; ++s)
            ap[s] = *(const bfrag*)&Ps[wave][l16][s * 32 + quad * 8];

        // --- O += P V ---
#pragma unroll
        for (int td = 0; td < 4; ++td) {
            const u16b* vrow = &Vt[vtbase + (size_t)(td * 16 + l16) * SEQ + kt];
#pragma unroll
            for (int s = 0; s < 2; ++s) {
                bfrag bv = *(const bfrag*)(vrow + s * 32 + quad * 8);
                ov[td] = __builtin_amdgcn_mfma_f32_16x16x32_bf16(ap[s], bv, ov[td], 0, 0, 0);
            }
        }
    }

    // epilogue: divide by l, store bf16
#pragma unroll
    for (int r = 0; r < 4; ++r) {
        const float inv = 1.f / lr[r];
#pragma unroll
        for (int td = 0; td < 4; ++td)
            Oo[qkbase + (size_t)(q0 + quad * 4 + r) * EMBED + td * 16 + l16] =
                f2b(ov[td][r] * inv);
    }
}

// ---------- launch ----------
extern "C" void kernel_launch(void* const* d_in, const int* in_sizes, int n_in,
                              void* d_out, int out_size, void* d_ws, size_t ws_size,
                              hipStream_t stream) {
    const float* query = (const float*)d_in[0];
    const float* key_  = (const float*)d_in[1];
    const float* value = (const float*)d_in[2];
    const float* Wq    = (const float*)d_in[3];
    const float* Wk    = (const float*)d_in[4];
    const float* Wv    = (const float*)d_in[5];
    const float* Wo    = (const float*)d_in[6];
    float* out = (float*)d_out;

    // bf16 workspace layout (byte offsets, 76 MB total <= 80 MB proven available)
    char* ws = (char*)d_ws;
    const size_t MB = 1024 * 1024;
    u16b* xq  = (u16b*)(ws + 0 * MB);    // 8 MB   [4096,1024]
    u16b* xk  = (u16b*)(ws + 8 * MB);
    u16b* xv  = (u16b*)(ws + 16 * MB);
    u16b* wq  = (u16b*)(ws + 24 * MB);   // 2 MB   [1024,1024]
    u16b* wk  = (u16b*)(ws + 26 * MB);
    u16b* wv  = (u16b*)(ws + 28 * MB);
    u16b* wo  = (u16b*)(ws + 30 * MB);
    u16b* wqt = (u16b*)(ws + 32 * MB);
    u16b* wkt = (u16b*)(ws + 34 * MB);
    u16b* gq  = (u16b*)(ws + 36 * MB);
    u16b* gk  = (u16b*)(ws + 38 * MB);
    u16b* wqo = (u16b*)(ws + 40 * MB);
    u16b* wko = (u16b*)(ws + 42 * MB);
    u16b* qp  = (u16b*)(ws + 44 * MB);   // 8 MB
    u16b* kp  = (u16b*)(ws + 52 * MB);
    u16b* vp  = (u16b*)(ws + 60 * MB);
    u16b* Vt  = (u16b*)(ws + 68 * MB);   // 8 MB
    u16b* ao  = xq;                      // reuse: xq dead after q-projection

    const int NE = MROWS * EMBED;   // 4M
    const int NW = EMBED * EMBED;   // 1M

    // converts
    convert_f2b<<<NE / 1024, 256, 0, stream>>>(query, xq, NE);
    convert_f2b<<<NE / 1024, 256, 0, stream>>>(key_,  xk, NE);
    convert_f2b<<<NE / 1024, 256, 0, stream>>>(value, xv, NE);
    convert_f2b<<<NW / 1024, 256, 0, stream>>>(Wq, wq, NW);
    convert_f2b<<<NW / 1024, 256, 0, stream>>>(Wk, wk, NW);
    convert_f2b<<<NW / 1024, 256, 0, stream>>>(Wv, wv, NW);
    convert_f2b<<<NW / 1024, 256, 0, stream>>>(Wo, wo, NW);
    transpose_f2b<<<dim3(32, 32), dim3(32, 8), 0, stream>>>(Wq, wqt, EMBED);
    transpose_f2b<<<dim3(32, 32), dim3(32, 8), 0, stream>>>(Wk, wkt, EMBED);

    const dim3 blk(256);
    const dim3 gW(EMBED / 128, EMBED / 128);   // 8x8
    const dim3 gP(EMBED / 128, MROWS / 128);   // 8x32

    // Grams: G = W^T W  ==  NT(Wt, Wt)
    gemm_nt_mfma<0><<<gW, blk, 0, stream>>>(wqt, wqt, nullptr, gq, nullptr, EMBED, EMBED, EMBED);
    gemm_nt_mfma<0><<<gW, blk, 0, stream>>>(wkt, wkt, nullptr, gk, nullptr, EMBED, EMBED, EMBED);
    // Orth: Wq_o = Wq - Wq@Gk (Gk symmetric -> NT), both from ORIGINAL weights
    gemm_nt_mfma<1><<<gW, blk, 0, stream>>>(wq, gk, Wq, wqo, nullptr, EMBED, EMBED, EMBED);
    gemm_nt_mfma<1><<<gW, blk, 0, stream>>>(wk, gq, Wk, wko, nullptr, EMBED, EMBED, EMBED);
    // Projections: x @ W^T
    gemm_nt_mfma<0><<<gP, blk, 0, stream>>>(xq, wqo, nullptr, qp, nullptr, MROWS, EMBED, EMBED);
    gemm_nt_mfma<0><<<gP, blk, 0, stream>>>(xk, wko, nullptr, kp, nullptr, MROWS, EMBED, EMBED);
    gemm_nt_mfma<0><<<gP, blk, 0, stream>>>(xv, wv,  nullptr, vp, nullptr, MROWS, EMBED, EMBED);
    // V transpose for PV B-operand
    transpose_v<<<dim3(SEQ / 64, NHEADS, BATCH), dim3(64, 4), 0, stream>>>(vp, Vt);
    // Attention
    flash_attn_mfma<<<dim3(SEQ / 64, NHEADS, BATCH), blk, 0, stream>>>(qp, kp, Vt, ao);
    // Output projection (fp32 out)
    gemm_nt_mfma<2><<<gP, blk, 0, stream>>>(ao, wo, nullptr, nullptr, out, MROWS, EMBED, EMBED);
}

// Round 3
// 443.532 us; speedup vs baseline: 12.2058x; 1.3730x over previous
//
#include <hip/hip_runtime.h>
#include <math.h>

constexpr int EMBED  = 1024;
constexpr int NHEADS = 16;
constexpr int HDIM   = 64;
constexpr int BATCH  = 2;
constexpr int SEQ    = 2048;
constexpr int MROWS  = BATCH * SEQ;  // 4096

typedef unsigned short u16b;  // bf16 storage
typedef __attribute__((ext_vector_type(8))) short bfrag;   // 8 bf16 (4 VGPRs)
typedef __attribute__((ext_vector_type(4))) float ffrag;   // 4 fp32 acc

// softmax scale folded with log2(e): exp(0.125*x) == exp2(0.18033688*x)
#define SCALE_Q 0.18033688f

__device__ __forceinline__ u16b f2b(float f) {          // RNE
    union { float f; unsigned u; } v; v.f = f;
    unsigned r = v.u + 0x7fffu + ((v.u >> 16) & 1u);
    return (u16b)(r >> 16);
}
__device__ __forceinline__ u16b f2b_fast(float f) {     // round-half-up, 2 ops
    union { float f; unsigned u; } v; v.f = f;
    return (u16b)((v.u + 0x8000u) >> 16);
}

__device__ __forceinline__ void gload_lds16(const u16b* g, u16b* l) {
    __builtin_amdgcn_global_load_lds(
        (const __attribute__((address_space(1))) void*)g,
        (__attribute__((address_space(3))) void*)l,
        16, 0, 0);
}

struct GemmPtrs {
    const u16b* A[3];
    const u16b* B[3];
    const float* D[3];
    u16b* Cb[3];
    float* Cf[3];
    float scale[3];
};

// ---------- prep kernels ----------

// all three fp32 activations -> bf16 in one launch (blockIdx.y picks array)
__global__ void prep_inputs(const float* __restrict__ q, const float* __restrict__ k,
                            const float* __restrict__ v,
                            u16b* __restrict__ oq, u16b* __restrict__ ok,
                            u16b* __restrict__ ov) {
    const int w = blockIdx.y;
    const float* src = (w == 0) ? q : (w == 1) ? k : v;
    u16b* dst = (w == 0) ? oq : (w == 1) ? ok : ov;
    const int i = blockIdx.x * 256 + threadIdx.x;
    float4 val = ((const float4*)src)[i];
    ushort4 o;
    o.x = f2b(val.x); o.y = f2b(val.y); o.z = f2b(val.z); o.w = f2b(val.w);
    ((ushort4*)dst)[i] = o;
}

// all four weights -> bf16 (+ transposed copies of Wq, Wk) in one launch
__global__ void prep_weights(const float* __restrict__ Wq, const float* __restrict__ Wk,
                             const float* __restrict__ Wv, const float* __restrict__ Wo,
                             u16b* __restrict__ wq, u16b* __restrict__ wk,
                             u16b* __restrict__ wv, u16b* __restrict__ wo,
                             u16b* __restrict__ wqt, u16b* __restrict__ wkt) {
    const int z = blockIdx.z;
    const float* src = (z == 0) ? Wq : (z == 1) ? Wk : (z == 2) ? Wv : Wo;
    u16b* dst  = (z == 0) ? wq : (z == 1) ? wk : (z == 2) ? wv : wo;
    u16b* dstT = (z == 0) ? wqt : (z == 1) ? wkt : nullptr;
    __shared__ float t[32][33];
    const int bx = blockIdx.x * 32, by = blockIdx.y * 32;
    const int x = threadIdx.x, y = threadIdx.y;  // (32,8)
#pragma unroll
    for (int r = 0; r < 4; ++r) {
        const int row = by + y + 8 * r;
        const float v = src[(size_t)row * EMBED + bx + x];
        dst[(size_t)row * EMBED + bx + x] = f2b(v);
        if (z < 2) t[y + 8 * r][x] = v;
    }
    if (z >= 2) return;
    __syncthreads();
#pragma unroll
    for (int r = 0; r < 4; ++r)
        dstT[(size_t)(bx + y + 8 * r) * EMBED + by + x] = f2b(t[x][y + 8 * r]);
}

// bf16 v [B,S,E] -> Vt [B,H,64,S]
__global__ void transpose_v(const u16b* __restrict__ vp, u16b* __restrict__ Vt) {
    __shared__ u16b t[64][65];
    const int s0 = blockIdx.x * 64, h = blockIdx.y, b = blockIdx.z;
    const int x = threadIdx.x, y = threadIdx.y;  // (64,4)
#pragma unroll
    for (int r = 0; r < 16; ++r) {
        int srow = y + 4 * r;
        t[srow][x] = vp[(size_t)(b * SEQ + s0 + srow) * EMBED + h * HDIM + x];
    }
    __syncthreads();
#pragma unroll
    for (int r = 0; r < 16; ++r) {
        int d = y + 4 * r;
        Vt[(size_t)((b * NHEADS + h) * HDIM + d) * SEQ + s0 + x] = t[x][d];
    }
}

// ---------- 64-tile bf16 MFMA NT GEMM (small matrices, z-batched) ----------
// MODE 0: Cb = f2b(scale*AB)   MODE 1: Cb = f2b(D - AB)
template<int MODE>
__global__ __launch_bounds__(256) void gemm64(GemmPtrs p, int M, int N, int K) {
    const int z = blockIdx.z;
    const u16b* __restrict__ A = p.A[z];
    const u16b* __restrict__ B = p.B[z];
    const float* __restrict__ D = p.D[z];
    u16b* __restrict__ Cb = p.Cb[z];
    const float scale = p.scale[z];

    __shared__ __align__(16) u16b As[64 * 32];
    __shared__ __align__(16) u16b Bs[64 * 32];

    const int tid = threadIdx.x;
    const int wave = tid >> 6, lane = tid & 63;
    const int quad = lane >> 4, l16 = lane & 15;
    const int wrow = wave >> 1, wcol = wave & 1;
    const int m0 = blockIdx.y * 64, n0 = blockIdx.x * 64;

    ffrag acc[2][2];
#pragma unroll
    for (int i = 0; i < 2; ++i)
#pragma unroll
        for (int j = 0; j < 2; ++j) acc[i][j] = ffrag{0.f, 0.f, 0.f, 0.f};

    const int srow = tid >> 2, schunk = tid & 3;  // 256 lanes stage 64 rows x 64B

    for (int kt = 0; kt < K; kt += 32) {
        gload_lds16(A + (size_t)(m0 + srow) * K + kt + schunk * 8, &As[wave * 512]);
        gload_lds16(B + (size_t)(n0 + srow) * K + kt + schunk * 8, &Bs[wave * 512]);
        __syncthreads();
        bfrag a[2], bv[2];
#pragma unroll
        for (int i = 0; i < 2; ++i)
            a[i] = *(const bfrag*)&As[(wrow * 32 + i * 16 + l16) * 32 + quad * 8];
#pragma unroll
        for (int j = 0; j < 2; ++j)
            bv[j] = *(const bfrag*)&Bs[(wcol * 32 + j * 16 + l16) * 32 + quad * 8];
#pragma unroll
        for (int i = 0; i < 2; ++i)
#pragma unroll
            for (int j = 0; j < 2; ++j)
                acc[i][j] = __builtin_amdgcn_mfma_f32_16x16x32_bf16(a[i], bv[j], acc[i][j], 0, 0, 0);
        __syncthreads();
    }

#pragma unroll
    for (int i = 0; i < 2; ++i)
#pragma unroll
        for (int j = 0; j < 2; ++j) {
            const int col = n0 + wcol * 32 + j * 16 + l16;
#pragma unroll
            for (int r = 0; r < 4; ++r) {
                const int row = m0 + wrow * 32 + i * 16 + quad * 4 + r;
                const size_t idx = (size_t)row * N + col;
                const float v = acc[i][j][r];
                if (MODE == 0) Cb[idx] = f2b(v * scale);
                else Cb[idx] = f2b(D[idx] - v);
            }
        }
}

// ---------- 128-tile bf16 MFMA NT GEMM (big matmuls, z-batched) ----------
// MODE 0: Cb = f2b(scale*AB)   MODE 2: Cf = AB (fp32)
template<int MODE>
__global__ __launch_bounds__(256) void gemm128(GemmPtrs p, int M, int N, int K) {
    const int z = blockIdx.z;
    const u16b* __restrict__ A = p.A[z];
    const u16b* __restrict__ B = p.B[z];
    u16b* __restrict__ Cb = p.Cb[z];
    float* __restrict__ Cf = p.Cf[z];
    const float scale = p.scale[z];

    constexpr int BK = 32;
    __shared__ __align__(16) u16b As[128 * BK];
    __shared__ __align__(16) u16b Bs[128 * BK];

    const int tid = threadIdx.x;
    const int wave = tid >> 6, lane = tid & 63;
    const int quad = lane >> 4, l16 = lane & 15;
    const int wrow = wave >> 1, wcol = wave & 1;
    const int m0 = blockIdx.y * 128, n0 = blockIdx.x * 128;

    ffrag acc[4][4];
#pragma unroll
    for (int i = 0; i < 4; ++i)
#pragma unroll
        for (int j = 0; j < 4; ++j) acc[i][j] = ffrag{0.f, 0.f, 0.f, 0.f};

    const int srow = lane >> 2, schunk = lane & 3;

    for (int kt = 0; kt < K; kt += BK) {
#pragma unroll
        for (int q = 0; q < 2; ++q) {
            int row = wave * 32 + q * 16;
            gload_lds16(A + (size_t)(m0 + row + srow) * K + kt + schunk * 8, &As[row * BK]);
            gload_lds16(B + (size_t)(n0 + row + srow) * K + kt + schunk * 8, &Bs[row * BK]);
        }
        __syncthreads();
        bfrag af[4], bfv[4];
#pragma unroll
        for (int i = 0; i < 4; ++i)
            af[i] = *(const bfrag*)&As[(wrow * 64 + i * 16 + l16) * BK + quad * 8];
#pragma unroll
        for (int j = 0; j < 4; ++j)
            bfv[j] = *(const bfrag*)&Bs[(wcol * 64 + j * 16 + l16) * BK + quad * 8];
#pragma unroll
        for (int i = 0; i < 4; ++i)
#pragma unroll
            for (int j = 0; j < 4; ++j)
                acc[i][j] = __builtin_amdgcn_mfma_f32_16x16x32_bf16(af[i], bfv[j], acc[i][j], 0, 0, 0);
        __syncthreads();
    }

#pragma unroll
    for (int i = 0; i < 4; ++i)
#pragma unroll
        for (int j = 0; j < 4; ++j) {
            const int col = n0 + wcol * 64 + j * 16 + l16;
#pragma unroll
            for (int r = 0; r < 4; ++r) {
                const int row = m0 + wrow * 64 + i * 16 + quad * 4 + r;
                const size_t idx = (size_t)row * N + col;
                const float v = acc[i][j][r];
                if (MODE == 0) Cb[idx] = f2b(v * scale);
                else Cf[idx] = v;
            }
        }
}

// ---------- flash attention, transposed scores ----------
// Q,K: [B,S,E] bf16 (q pre-scaled by SCALE_Q); Vt: [B,H,64,S]; O: [B,S,E] bf16.
// S^T = K Q^T: C-layout rows = keys (quad*4+r, 4 tiles), cols = q (l16).
// Softmax reduction over keys: 15 in-reg ops + 2 quad-shuffles; m,l are per-lane scalars.
// O^T = Vt * P (P as B-operand via per-wave LDS round-trip).
__global__ __launch_bounds__(256) void flash_attn_t(
    const u16b* __restrict__ Q, const u16b* __restrict__ Km,
    const u16b* __restrict__ Vt, u16b* __restrict__ Oo)
{
    const int tid = threadIdx.x;
    const int wave = tid >> 6, lane = tid & 63;
    const int quad = lane >> 4, l16 = lane & 15;
    const int qt = blockIdx.x, h = blockIdx.y, b = blockIdx.z;
    const int q0 = qt * 64 + wave * 16;

    __shared__ __align__(16) u16b Ps[4][16][72];  // per-wave P[q][key], stride 72 (+8 pad)

    const size_t qkbase = (size_t)b * SEQ * EMBED + h * HDIM;
    const size_t vtbase = (size_t)(b * NHEADS + h) * HDIM * SEQ;

    // Q as B-operand: B[n=l16][k=quad*8+j]
    bfrag bq[2];
#pragma unroll
    for (int s = 0; s < 2; ++s)
        bq[s] = *(const bfrag*)&Q[qkbase + (size_t)(q0 + l16) * EMBED + s * 32 + quad * 8];

    ffrag ov[4];
#pragma unroll
    for (int t = 0; t < 4; ++t) ov[t] = ffrag{0.f, 0.f, 0.f, 0.f};
    float m_run = -1e30f, l_run = 0.f;

    const u16b* kptr = Km + qkbase + (size_t)l16 * EMBED + quad * 8;
    const u16b* vptr = Vt + vtbase + (size_t)l16 * SEQ + quad * 8;

    for (int kt = 0; kt < SEQ; kt += 64) {
        // --- S^T = K Q^T : keys t*16+quad*4+r (rows), q-col l16 ---
        ffrag St[4];
#pragma unroll
        for (int t = 0; t < 4; ++t) St[t] = ffrag{0.f, 0.f, 0.f, 0.f};
#pragma unroll
        for (int t = 0; t < 4; ++t) {
            const u16b* kr = kptr + (size_t)(kt + t * 16) * EMBED;
#pragma unroll
            for (int s = 0; s < 2; ++s) {
                bfrag ak = *(const bfrag*)(kr + s * 32);
                St[t] = __builtin_amdgcn_mfma_f32_16x16x32_bf16(ak, bq[s], St[t], 0, 0, 0);
            }
        }

        // --- column max: in-register over 16 vals + 2 cross-quad shuffles ---
        float mx = St[0][0];
#pragma unroll
        for (int t = 0; t < 4; ++t)
#pragma unroll
            for (int r = 0; r < 4; ++r) mx = fmaxf(mx, St[t][r]);
        mx = fmaxf(mx, __shfl_xor(mx, 16));
        mx = fmaxf(mx, __shfl_xor(mx, 32));
        const float mnew = fmaxf(m_run, mx);
        const float al = __builtin_amdgcn_exp2f(m_run - mnew);

        // --- exp (exp2 domain; scale folded into q) + column sum ---
        float rs = 0.f;
#pragma unroll
        for (int t = 0; t < 4; ++t)
#pragma unroll
            for (int r = 0; r < 4; ++r) {
                const float pv = __builtin_amdgcn_exp2f(St[t][r] - mnew);
                St[t][r] = pv;
                rs += pv;
            }
        rs += __shfl_xor(rs, 16);
        rs += __shfl_xor(rs, 32);
        l_run = l_run * al + rs;
        m_run = mnew;
#pragma unroll
        for (int t = 0; t < 4; ++t)
#pragma unroll
            for (int r = 0; r < 4; ++r) ov[t][r] *= al;

        // --- pack P[q=l16][key] to LDS (ds_write_b64 per t) ---
#pragma unroll
        for (int t = 0; t < 4; ++t) {
            ushort4 pk;
            pk.x = f2b_fast(St[t][0]); pk.y = f2b_fast(St[t][1]);
            pk.z = f2b_fast(St[t][2]); pk.w = f2b_fast(St[t][3]);
            *(ushort4*)&Ps[wave][l16][t * 16 + quad * 4] = pk;
        }
        asm volatile("s_waitcnt lgkmcnt(0)" ::: "memory");
        bfrag bp[2];
#pragma unroll
        for (int s = 0; s < 2; ++s)
            bp[s] = *(const bfrag*)&Ps[wave][l16][s * 32 + quad * 8];

        // --- O^T += Vt * P : rows d = t*16+quad*4+r, cols q = l16 ---
#pragma unroll
        for (int t = 0; t < 4; ++t) {
            const u16b* vr = vptr + (size_t)(t * 16) * SEQ + kt;
#pragma unroll
            for (int s = 0; s < 2; ++s) {
                bfrag av = *(const bfrag*)(vr + s * 32);
                ov[t] = __builtin_amdgcn_mfma_f32_16x16x32_bf16(av, bp[s], ov[t], 0, 0, 0);
            }
        }
    }

    // epilogue: O[q0+l16][h*64 + t*16 + quad*4 + r] = ov[t][r] / l
    const float inv = 1.f / l_run;
#pragma unroll
    for (int t = 0; t < 4; ++t) {
        ushort4 o;
        o.x = f2b(ov[t][0] * inv); o.y = f2b(ov[t][1] * inv);
        o.z = f2b(ov[t][2] * inv); o.w = f2b(ov[t][3] * inv);
        *(ushort4*)&Oo[qkbase + (size_t)(q0 + l16) * EMBED + t * 16 + quad * 4] = o;
    }
}

// ---------- launch ----------
extern "C" void kernel_launch(void* const* d_in, const int* in_sizes, int n_in,
                              void* d_out, int out_size, void* d_ws, size_t ws_size,
                              hipStream_t stream) {
    const float* query = (const float*)d_in[0];
    const float* key_  = (const float*)d_in[1];
    const float* value = (const float*)d_in[2];
    const float* Wq    = (const float*)d_in[3];
    const float* Wk    = (const float*)d_in[4];
    const float* Wv    = (const float*)d_in[5];
    const float* Wo    = (const float*)d_in[6];
    float* out = (float*)d_out;

    char* ws = (char*)d_ws;
    const size_t MB = 1024 * 1024;
    u16b* xq  = (u16b*)(ws + 0 * MB);    // 8 MB  [4096,1024]
    u16b* xk  = (u16b*)(ws + 8 * MB);
    u16b* xv  = (u16b*)(ws + 16 * MB);
    u16b* wq  = (u16b*)(ws + 24 * MB);   // 2 MB  [1024,1024]
    u16b* wk  = (u16b*)(ws + 26 * MB);
    u16b* wv  = (u16b*)(ws + 28 * MB);
    u16b* wo  = (u16b*)(ws + 30 * MB);
    u16b* wqt = (u16b*)(ws + 32 * MB);
    u16b* wkt = (u16b*)(ws + 34 * MB);
    u16b* gq  = (u16b*)(ws + 36 * MB);
    u16b* gk  = (u16b*)(ws + 38 * MB);
    u16b* wqo = (u16b*)(ws + 40 * MB);
    u16b* wko = (u16b*)(ws + 42 * MB);
    u16b* qp  = (u16b*)(ws + 44 * MB);   // 8 MB
    u16b* kp  = (u16b*)(ws + 52 * MB);
    u16b* vp  = (u16b*)(ws + 60 * MB);
    u16b* Vt  = (u16b*)(ws + 68 * MB);   // 8 MB
    u16b* ao  = xq;                      // xq dead after projections

    // 1) converts (2 launches)
    prep_inputs<<<dim3(MROWS * EMBED / 1024, 3), dim3(256), 0, stream>>>(
        query, key_, value, xq, xk, xv);
    prep_weights<<<dim3(32, 32, 4), dim3(32, 8), 0, stream>>>(
        Wq, Wk, Wv, Wo, wq, wk, wv, wo, wqt, wkt);

    // 2) Grams: Gq = Wq^T Wq = NT(wqt,wqt), Gk likewise (z-batched, 512 blocks)
    {
        GemmPtrs p{};
        p.A[0] = wqt; p.B[0] = wqt; p.Cb[0] = gq; p.scale[0] = 1.f;
        p.A[1] = wkt; p.B[1] = wkt; p.Cb[1] = gk; p.scale[1] = 1.f;
        gemm64<0><<<dim3(16, 16, 2), dim3(256), 0, stream>>>(p, EMBED, EMBED, EMBED);
    }
    // 3) Orth: Wq_o = Wq - Wq@Gk, Wk_o = Wk - Wk@Gq (G symmetric -> NT)
    {
        GemmPtrs p{};
        p.A[0] = wq; p.B[0] = gk; p.D[0] = Wq; p.Cb[0] = wqo;
        p.A[1] = wk; p.B[1] = gq; p.D[1] = Wk; p.Cb[1] = wko;
        gemm64<1><<<dim3(16, 16, 2), dim3(256), 0, stream>>>(p, EMBED, EMBED, EMBED);
    }
    // 4) Projections x @ W^T, z-batched (768 blocks); q pre-scaled for exp2 softmax
    {
        GemmPtrs p{};
        p.A[0] = xq; p.B[0] = wqo; p.Cb[0] = qp; p.scale[0] = SCALE_Q;
        p.A[1] = xk; p.B[1] = wko; p.Cb[1] = kp; p.scale[1] = 1.f;
        p.A[2] = xv; p.B[2] = wv;  p.Cb[2] = vp; p.scale[2] = 1.f;
        gemm128<0><<<dim3(EMBED / 128, MROWS / 128, 3), dim3(256), 0, stream>>>(
            p, MROWS, EMBED, EMBED);
    }
    // 5) V transpose for PV A-operand
    transpose_v<<<dim3(SEQ / 64, NHEADS, BATCH), dim3(64, 4), 0, stream>>>(vp, Vt);
    // 6) Attention (transposed-score flash)
    flash_attn_t<<<dim3(SEQ / 64, NHEADS, BATCH), dim3(256), 0, stream>>>(qp, kp, Vt, ao);
    // 7) Output projection (fp32 out)
    {
        GemmPtrs p{};
        p.A[0] = ao; p.B[0] = wo; p.Cf[0] = out; p.scale[0] = 1.f;
        gemm128<2><<<dim3(EMBED / 128, MROWS / 128, 1), dim3(256), 0, stream>>>(
            p, MROWS, EMBED, EMBED);
    }
}